// Round 1
// baseline (333.231 us; speedup 1.0000x reference)
//
#include <hip/hip_runtime.h>

#define BB 4
#define HH 512
#define WW 512
#define KK 7
#define PP 3
#define CC 256

// Scatter active-site linear index into dense idx_map (pre-filled with -1).
__global__ void smconv_scatter(const int* __restrict__ idx,
                               int* __restrict__ idx_map, int n) {
    int i = blockIdx.x * blockDim.x + threadIdx.x;
    if (i >= n) return;
    int b = idx[i * 3 + 0];
    int y = idx[i * 3 + 1];
    int x = idx[i * 3 + 2];
    idx_map[((size_t)b * HH + y) * WW + x] = i;
}

// Transpose weight (C, K, K) -> (K*K, C) so channel-major loads coalesce.
__global__ void smconv_wt(const float* __restrict__ w, float* __restrict__ w_t) {
    int i = blockIdx.x * blockDim.x + threadIdx.x;
    if (i >= KK * KK * CC) return;
    int tap = i / CC;
    int c = i - tap * CC;
    w_t[i] = w[c * KK * KK + tap];
}

// One wave (64 lanes) per output site; each lane owns 4 channels (float4).
__global__ void __launch_bounds__(256)
smconv_conv(const float* __restrict__ feat,
            const int* __restrict__ idx,
            const float* __restrict__ w_t,
            const float* __restrict__ bias,
            const int* __restrict__ idx_map,
            float* __restrict__ out, int n) {
    const int group = threadIdx.x >> 6;   // wave id within block (0..3)
    const int lane  = threadIdx.x & 63;
    const int site  = blockIdx.x * 4 + group;
    if (site >= n) return;

    // Lane 'tap' (tap < 49) computes neighbor index for its tap.
    int nb = -1;
    if (lane < KK * KK) {
        int b = idx[site * 3 + 0];
        int y = idx[site * 3 + 1];
        int x = idx[site * 3 + 2];
        int dy = lane / KK - PP;
        int dx = lane % KK - PP;
        int yy = y + dy;
        int xx = x + dx;
        if (yy >= 0 && yy < HH && xx >= 0 && xx < WW) {
            nb = idx_map[((size_t)b * HH + yy) * WW + xx];
        }
    }

    // Wave-uniform mask of active taps (bits 49..63 are 0 since nb==-1 there).
    unsigned long long mask = __ballot(nb >= 0);

    const int c4 = lane * 4;
    float4 acc = make_float4(0.f, 0.f, 0.f, 0.f);

    while (mask) {
        int tap = __ffsll((long long)mask) - 1;
        mask &= mask - 1;
        int nbi = __shfl(nb, tap);  // wave-uniform neighbor row
        float4 f = *(const float4*)(feat + (size_t)nbi * CC + c4);
        float4 wv = *(const float4*)(w_t + tap * CC + c4);
        acc.x = fmaf(f.x, wv.x, acc.x);
        acc.y = fmaf(f.y, wv.y, acc.y);
        acc.z = fmaf(f.z, wv.z, acc.z);
        acc.w = fmaf(f.w, wv.w, acc.w);
    }

    float4 bv = *(const float4*)(bias + c4);
    acc.x += bv.x;
    acc.y += bv.y;
    acc.z += bv.z;
    acc.w += bv.w;
    *(float4*)(out + (size_t)site * CC + c4) = acc;
}

extern "C" void kernel_launch(void* const* d_in, const int* in_sizes, int n_in,
                              void* d_out, int out_size, void* d_ws, size_t ws_size,
                              hipStream_t stream) {
    const float* feat = (const float*)d_in[0];
    const int*   idx  = (const int*)d_in[1];
    const float* w    = (const float*)d_in[2];
    const float* bias = (const float*)d_in[3];
    float* out = (float*)d_out;

    const int n = in_sizes[0] / CC;  // number of active sites

    int*   idx_map = (int*)d_ws;
    float* w_t     = (float*)((char*)d_ws + (size_t)BB * HH * WW * sizeof(int));

    // 1) idx_map = -1
    hipMemsetAsync(idx_map, 0xFF, (size_t)BB * HH * WW * sizeof(int), stream);
    // 2) scatter site ids
    smconv_scatter<<<(n + 255) / 256, 256, 0, stream>>>(idx, idx_map, n);
    // 3) transpose weights to (tap, C)
    smconv_wt<<<(KK * KK * CC + 255) / 256, 256, 0, stream>>>(w, w_t);
    // 4) gather conv: one wave per site, 4 sites per block
    smconv_conv<<<(n + 3) / 4, 256, 0, stream>>>(feat, idx, w_t, bias, idx_map, out, n);
}

// Round 2
// 271.963 us; speedup vs baseline: 1.2253x; 1.2253x over previous
//
#include <hip/hip_runtime.h>

#define BB 4
#define HH 512
#define WW 512
#define KK 7
#define PP 3
#define CC 256
#define TS 32                 // spatial tile size
#define HALO 3
#define TD (TS + 2 * HALO)    // 38: tile + halo

// Scatter active-site linear index into dense idx_map (pre-filled with -1).
__global__ void smconv_scatter(const int* __restrict__ idx,
                               int* __restrict__ idx_map, int n) {
    int i = blockIdx.x * blockDim.x + threadIdx.x;
    if (i >= n) return;
    int b = idx[i * 3 + 0];
    int y = idx[i * 3 + 1];
    int x = idx[i * 3 + 2];
    idx_map[((size_t)b * HH + y) * WW + x] = i;
}

// Transpose weight (C, K, K) -> (K*K, C) so channel-major loads coalesce.
__global__ void smconv_wt(const float* __restrict__ w, float* __restrict__ w_t) {
    int i = blockIdx.x * blockDim.x + threadIdx.x;
    if (i >= KK * KK * CC) return;
    int tap = i / CC;
    int c = i - tap * CC;
    w_t[i] = w[c * KK * KK + tap];
}

// One block per 32x32 spatial tile; 8 waves; one wave per active site at a
// time, each lane owns 4 channels (float4). Neighbor ids come from an LDS
// copy of the tile+halo idx_map.
__global__ void __launch_bounds__(512)
smconv_conv_tile(const float* __restrict__ feat,
                 const float* __restrict__ w_t,
                 const float* __restrict__ bias,
                 const int* __restrict__ idx_map,
                 float* __restrict__ out) {
    __shared__ int smap[TD * TD];
    __shared__ unsigned short lst[TS * TS];
    __shared__ int cnt;

    const int tid = threadIdx.x;
    const int b  = blockIdx.z;
    const int y0 = blockIdx.y * TS - HALO;
    const int x0 = blockIdx.x * TS - HALO;

    if (tid == 0) cnt = 0;

    // Stage tile+halo idx_map into LDS (-1 outside image).
    for (int i = tid; i < TD * TD; i += 512) {
        int gy = y0 + i / TD;
        int gx = x0 + i % TD;
        int v = -1;
        if (gy >= 0 && gy < HH && gx >= 0 && gx < WW)
            v = idx_map[((size_t)b * HH + gy) * WW + gx];
        smap[i] = v;
    }
    __syncthreads();

    // Compact active cells of the 32x32 core into an LDS list.
    for (int i = tid; i < TS * TS; i += 512) {
        int iy = i >> 5;
        int ix = i & (TS - 1);
        if (smap[(iy + HALO) * TD + (ix + HALO)] >= 0) {
            int p = atomicAdd(&cnt, 1);
            lst[p] = (unsigned short)i;
        }
    }
    __syncthreads();

    const int wave = tid >> 6;
    const int lane = tid & 63;
    const int c4   = lane * 4;
    const int n    = cnt;

    const float4 bv = *(const float4*)(bias + c4);

    for (int e = wave; e < n; e += 8) {
        const int pos = lst[e];
        const int iy = pos >> 5;
        const int ix = pos & (TS - 1);

        int nb = -1;
        if (lane < KK * KK)
            nb = smap[(iy + lane / KK) * TD + (ix + lane % KK)];

        // Center tap (tap 24) is this site's own id.
        const int site = __shfl(nb, PP * KK + PP);

        unsigned long long mask = __ballot(nb >= 0);
        float4 acc = make_float4(0.f, 0.f, 0.f, 0.f);

        while (mask) {
            int tap = __ffsll((long long)mask) - 1;
            mask &= mask - 1;
            int nbi = __shfl(nb, tap);  // wave-uniform neighbor row
            float4 f  = *(const float4*)(feat + (size_t)nbi * CC + c4);
            float4 wv = *(const float4*)(w_t + tap * CC + c4);
            acc.x = fmaf(f.x, wv.x, acc.x);
            acc.y = fmaf(f.y, wv.y, acc.y);
            acc.z = fmaf(f.z, wv.z, acc.z);
            acc.w = fmaf(f.w, wv.w, acc.w);
        }

        float4 o = make_float4(acc.x + bv.x, acc.y + bv.y,
                               acc.z + bv.z, acc.w + bv.w);
        *(float4*)(out + (size_t)site * CC + c4) = o;
    }
}

extern "C" void kernel_launch(void* const* d_in, const int* in_sizes, int n_in,
                              void* d_out, int out_size, void* d_ws, size_t ws_size,
                              hipStream_t stream) {
    const float* feat = (const float*)d_in[0];
    const int*   idx  = (const int*)d_in[1];
    const float* w    = (const float*)d_in[2];
    const float* bias = (const float*)d_in[3];
    float* out = (float*)d_out;

    const int n = in_sizes[0] / CC;  // number of active sites

    int*   idx_map = (int*)d_ws;
    float* w_t     = (float*)((char*)d_ws + (size_t)BB * HH * WW * sizeof(int));

    // 1) idx_map = -1
    hipMemsetAsync(idx_map, 0xFF, (size_t)BB * HH * WW * sizeof(int), stream);
    // 2) scatter site ids
    smconv_scatter<<<(n + 255) / 256, 256, 0, stream>>>(idx, idx_map, n);
    // 3) transpose weights to (tap, C)
    smconv_wt<<<(KK * KK * CC + 255) / 256, 256, 0, stream>>>(w, w_t);
    // 4) tiled gather conv: one block per 32x32 tile
    dim3 grid(WW / TS, HH / TS, BB);
    smconv_conv_tile<<<grid, 512, 0, stream>>>(feat, w_t, bias, idx_map, out);
}